// Round 2
// baseline (1501.389 us; speedup 1.0000x reference)
//
#include <hip/hip_runtime.h>

// Problem constants
#define NB 128
#define NC 256
#define HX 31
#define WX 31
#define HC 25          // corr spatial (31-7+1)
#define WC 25
#define HO 23          // head output spatial (25-3+1)
#define WO 23
#define CHUNKS 16      // channel chunks per batch item -> 2048 blocks
#define CPB (NC / CHUNKS)    // 16 channels per block
#define GRP 8                // channels per group iteration (25 threads each) -> 2 even groups
#define ZCH 56               // z: 7 rows * 8 stride (16B-aligned rows)
#define WCH 48               // weights: 45 padded to 48 (12 float4)
#define CCH (HC * WC)        // 625

#define NPIX (HO * WO)               // 529
#define HEAT_SZ (NB * NPIX)          // 67712
#define REG_SZ  (NB * 4 * NPIX)      // 270848
#define OUT_TOTAL (HEAT_SZ + REG_SZ) // 338560
#define NSTRIP (HO * 12)             // 276 two-pixel strips per image
#define PART_STRIDE (5 * NPIX)       // 2645 floats per (n,chunk) partial
#define WS_NEED ((size_t)NB * CHUNKS * PART_STRIDE * sizeof(float))

// unaligned-capable float4 (rows start at arbitrary dword offsets)
typedef float f4v __attribute__((ext_vector_type(4), aligned(4)));

// Fallback path only: writes bias into d_out (harness poisons d_out before launch).
__global__ void init_out_kernel(float* __restrict__ out,
                                const float* __restrict__ heat_b,
                                const float* __restrict__ reg_b) {
    int i = blockIdx.x * 256 + threadIdx.x;
    if (i >= OUT_TOTAL) return;
    if (i < HEAT_SZ) {
        out[i] = heat_b[0];
    } else {
        int j = i - HEAT_SZ;
        int o = (j / NPIX) & 3;
        out[i] = reg_b[o];
    }
}

// Reduce 16 per-chunk partials + bias -> final outputs. Overwrites poison fully.
__global__ void reduce_kernel(const float* __restrict__ part,
                              const float* __restrict__ heat_b,
                              const float* __restrict__ reg_b,
                              float* __restrict__ out) {
    int i = blockIdx.x * 256 + threadIdx.x;
    if (i >= OUT_TOTAL) return;
    int n, o, p;
    float b;
    if (i < HEAT_SZ) {
        n = i / NPIX; p = i - n * NPIX; o = 0; b = heat_b[0];
    } else {
        int j = i - HEAT_SZ;
        n = j / (4 * NPIX);
        int rm = j - n * 4 * NPIX;
        int r = rm / NPIX;
        p = rm - r * NPIX;
        o = 1 + r;
        b = reg_b[r];
    }
    const float* src = part + (size_t)n * CHUNKS * PART_STRIDE + o * NPIX + p;
    float s = b;
    #pragma unroll
    for (int c = 0; c < CHUNKS; ++c) s += src[(size_t)c * PART_STRIDE];
    out[i] = s;
}

// Fused exact-corr + head kernel, v4:
//  - CPB=16/GRP=8: two even corr groups (no G=2 tail pass)
//  - LDS ~24.9KB -> 6 blocks/CU resident (24 waves/CU) for latency hiding
//  - head phase: 2-pixel strips, vectorized LDS row reads (6 instrs vs 18)
//  - USE_WS: exclusive partial outputs, no atomics
template <bool USE_WS>
__launch_bounds__(256, 6)
__global__ void fused_head_kernel(const float* __restrict__ xf,
                                  const float* __restrict__ zf,
                                  const float* __restrict__ hw,
                                  const float* __restrict__ rw,
                                  float* __restrict__ out) {
    __shared__ __align__(16) float cs[GRP * CCH + 8];   // 20.0 KB (+pad for strip overread)
    __shared__ __align__(16) float zs[GRP * ZCH];       // 1.8 KB
    __shared__ __align__(16) float ws[CPB * WCH];       // 3.0 KB

    const int tid = threadIdx.x;
    const int n = blockIdx.x >> 4;
    const int chunk = blockIdx.x & 15;
    const int cbase = chunk * CPB;

    // corr mapping: 25 threads/channel, each owns an exact 5x5 corr tile
    const int cl = tid / 25;               // channel-in-group (>=GRP -> idle)
    const int tt = tid % 25;
    const int tr = tt / 5, tc = tt % 5;
    const int i0 = tr * 5, j0 = tc * 5;

    // head mapping: 2-pixel strips; strip s -> row s/12, cols 2*(s%12), 2*(s%12)+1
    const int sA = tid;                       // 0..255, always valid (< 276)
    const int syA = sA / 12, sxA = sA - syA * 12;
    const int cA = 2 * sxA;
    const int offA = syA * WC + cA;
    const int sB = tid + 256;                 // valid only for tid < 20
    const bool hasB = (sB < NSTRIP);
    const int syB = sB / 12, sxB = sB - syB * 12;
    const int cB = 2 * sxB;
    const int offB = hasB ? (syB * WC + cB) : 0;

    float aH_A0 = 0.f, aH_A1 = 0.f, aH_B0 = 0.f, aH_B1 = 0.f;
    float aR_A0[4] = {0.f, 0.f, 0.f, 0.f};
    float aR_A1[4] = {0.f, 0.f, 0.f, 0.f};
    float aR_B0[4] = {0.f, 0.f, 0.f, 0.f};
    float aR_B1[4] = {0.f, 0.f, 0.f, 0.f};

    const float* xn = xf + ((size_t)n * NC + cbase) * (HX * WX);
    const float* zn = zf + ((size_t)n * NC + cbase) * 49;

    // ---- stage all 16 channels' head weights once ----
    for (int idx = tid; idx < CPB * 45; idx += 256) {
        int ch = idx / 45, j = idx - ch * 45;
        int c = cbase + ch;
        float v;
        if (j < 9) {
            v = hw[c * 9 + j];
        } else {
            int o = (j - 9) / 9;
            int jj = (j - 9) - o * 9;
            v = rw[((size_t)o * NC + c) * 9 + jj];
        }
        ws[ch * WCH + j] = v;
    }

    for (int g0 = 0; g0 < CPB; g0 += GRP) {
        // ---- stage z, rows padded to stride 8 ----
        for (int idx = tid; idx < GRP * 49; idx += 256) {
            int ch = idx / 49, q = idx - ch * 49;
            int u = q / 7, v = q - u * 7;
            zs[ch * ZCH + u * 8 + v] = zn[(size_t)(g0 + ch) * 49 + q];
        }
        __syncthreads();

        // ---- exact corr: x rows from global, pipelined one row ahead ----
        if (cl < GRP) {
            const float* xb = xn + (size_t)(g0 + cl) * (HX * WX) + i0 * WX + j0;
            const float* zb = zs + cl * ZCH;

            float cacc[5][5];
            #pragma unroll
            for (int r = 0; r < 5; ++r)
                #pragma unroll
                for (int b = 0; b < 5; ++b) cacc[r][b] = 0.f;

            f4v c0 = *(const f4v*)(xb);
            f4v c1 = *(const f4v*)(xb + 4);
            f4v c2 = *(const f4v*)(xb + 7);   // cols j0+7..j0+10 (max col 30)

            #pragma unroll
            for (int rl = 0; rl < 11; ++rl) {
                f4v n0, n1, n2;
                if (rl < 10) {
                    const float* rp = xb + (rl + 1) * WX;
                    n0 = *(const f4v*)(rp);
                    n1 = *(const f4v*)(rp + 4);
                    n2 = *(const f4v*)(rp + 7);
                }
                const float xr[11] = {c0.x, c0.y, c0.z, c0.w,
                                      c1.x, c1.y, c1.z, c1.w,
                                      c2.y, c2.z, c2.w};
                #pragma unroll
                for (int u = 0; u < 7; ++u) {
                    const int r = rl - u;           // folds at compile time
                    if (r >= 0 && r < 5) {
                        f4v za = *(const f4v*)(zb + u * 8);      // broadcast
                        f4v zc = *(const f4v*)(zb + u * 8 + 4);
                        const float zz[7] = {za.x, za.y, za.z, za.w,
                                             zc.x, zc.y, zc.z};
                        #pragma unroll
                        for (int v = 0; v < 7; ++v)
                            #pragma unroll
                            for (int b = 0; b < 5; ++b)
                                cacc[r][b] = fmaf(zz[v], xr[b + v], cacc[r][b]);
                    }
                }
                if (rl < 10) { c0 = n0; c1 = n1; c2 = n2; }
            }
            float* cb = cs + cl * CCH + i0 * WC + j0;
            #pragma unroll
            for (int r = 0; r < 5; ++r)
                #pragma unroll
                for (int b = 0; b < 5; ++b) cb[r * WC + b] = cacc[r][b];
        }
        __syncthreads();

        // ---- conv heads: 2-pixel strips, vector LDS row reads ----
        for (int clc = 0; clc < GRP; ++clc) {
            float w[48];
            {
                const f4v* wp = (const f4v*)(ws + (size_t)(g0 + clc) * WCH);
                #pragma unroll
                for (int q = 0; q < 12; ++q) {     // broadcast reads
                    f4v t = wp[q];
                    w[q * 4 + 0] = t.x; w[q * 4 + 1] = t.y;
                    w[q * 4 + 2] = t.z; w[q * 4 + 3] = t.w;
                }
            }
            const float* cc = cs + clc * CCH;

            {   // strip A (all threads)
                const float* base = cc + offA;
                #pragma unroll
                for (int dy = 0; dy < 3; ++dy) {
                    f4v f = *(const f4v*)(base + dy * WC);
                    #pragma unroll
                    for (int dx = 0; dx < 3; ++dx) {
                        const int k = dy * 3 + dx;
                        const float v0 = f[dx];
                        const float v1 = f[dx + 1];
                        aH_A0 = fmaf(v0, w[k], aH_A0);
                        aH_A1 = fmaf(v1, w[k], aH_A1);
                        #pragma unroll
                        for (int o = 0; o < 4; ++o) {
                            aR_A0[o] = fmaf(v0, w[9 + 9 * o + k], aR_A0[o]);
                            aR_A1[o] = fmaf(v1, w[9 + 9 * o + k], aR_A1[o]);
                        }
                    }
                }
            }
            if (hasB) {   // strip B (tid < 20)
                const float* base = cc + offB;
                #pragma unroll
                for (int dy = 0; dy < 3; ++dy) {
                    f4v f = *(const f4v*)(base + dy * WC);
                    #pragma unroll
                    for (int dx = 0; dx < 3; ++dx) {
                        const int k = dy * 3 + dx;
                        const float v0 = f[dx];
                        const float v1 = f[dx + 1];
                        aH_B0 = fmaf(v0, w[k], aH_B0);
                        aH_B1 = fmaf(v1, w[k], aH_B1);
                        #pragma unroll
                        for (int o = 0; o < 4; ++o) {
                            aR_B0[o] = fmaf(v0, w[9 + 9 * o + k], aR_B0[o]);
                            aR_B1[o] = fmaf(v1, w[9 + 9 * o + k], aR_B1[o]);
                        }
                    }
                }
            }
        }
        __syncthreads();
    }

    // ---- epilogue ----
    if (USE_WS) {
        // exclusive partial region for this (n, chunk): plain coalesced stores
        float* part = out + (size_t)(n * CHUNKS + chunk) * PART_STRIDE;
        const int pA = syA * WO + cA;
        part[pA] = aH_A0;
        #pragma unroll
        for (int o = 0; o < 4; ++o) part[(1 + o) * NPIX + pA] = aR_A0[o];
        if (cA + 1 < WO) {
            part[pA + 1] = aH_A1;
            #pragma unroll
            for (int o = 0; o < 4; ++o) part[(1 + o) * NPIX + pA + 1] = aR_A1[o];
        }
        if (hasB) {
            const int pB = syB * WO + cB;
            part[pB] = aH_B0;
            #pragma unroll
            for (int o = 0; o < 4; ++o) part[(1 + o) * NPIX + pB] = aR_B0[o];
            if (cB + 1 < WO) {
                part[pB + 1] = aH_B1;
                #pragma unroll
                for (int o = 0; o < 4; ++o) part[(1 + o) * NPIX + pB + 1] = aR_B1[o];
            }
        }
    } else {
        // atomic fallback (bias pre-written by init kernel)
        float* outH = out + n * NPIX;
        float* outR = out + HEAT_SZ + (size_t)n * 4 * NPIX;
        const int pA = syA * WO + cA;
        atomicAdd(&outH[pA], aH_A0);
        #pragma unroll
        for (int o = 0; o < 4; ++o) atomicAdd(&outR[o * NPIX + pA], aR_A0[o]);
        if (cA + 1 < WO) {
            atomicAdd(&outH[pA + 1], aH_A1);
            #pragma unroll
            for (int o = 0; o < 4; ++o) atomicAdd(&outR[o * NPIX + pA + 1], aR_A1[o]);
        }
        if (hasB) {
            const int pB = syB * WO + cB;
            atomicAdd(&outH[pB], aH_B0);
            #pragma unroll
            for (int o = 0; o < 4; ++o) atomicAdd(&outR[o * NPIX + pB], aR_B0[o]);
            if (cB + 1 < WO) {
                atomicAdd(&outH[pB + 1], aH_B1);
                #pragma unroll
                for (int o = 0; o < 4; ++o) atomicAdd(&outR[o * NPIX + pB + 1], aR_B1[o]);
            }
        }
    }
}

extern "C" void kernel_launch(void* const* d_in, const int* in_sizes, int n_in,
                              void* d_out, int out_size, void* d_ws, size_t ws_size,
                              hipStream_t stream) {
    const float* x_f    = (const float*)d_in[0];
    const float* z_f    = (const float*)d_in[1];
    const float* heat_w = (const float*)d_in[2];
    const float* heat_b = (const float*)d_in[3];
    const float* reg_w  = (const float*)d_in[4];
    const float* reg_b  = (const float*)d_in[5];
    float* out = (float*)d_out;

    if (d_ws != nullptr && ws_size >= WS_NEED) {
        fused_head_kernel<true><<<NB * CHUNKS, 256, 0, stream>>>(
            x_f, z_f, heat_w, reg_w, (float*)d_ws);
        reduce_kernel<<<(OUT_TOTAL + 255) / 256, 256, 0, stream>>>(
            (const float*)d_ws, heat_b, reg_b, out);
    } else {
        init_out_kernel<<<(OUT_TOTAL + 255) / 256, 256, 0, stream>>>(out, heat_b, reg_b);
        fused_head_kernel<false><<<NB * CHUNKS, 256, 0, stream>>>(
            x_f, z_f, heat_w, reg_w, out);
    }
}

// Round 4
// 1203.968 us; speedup vs baseline: 1.2470x; 1.2470x over previous
//
#include <hip/hip_runtime.h>

// Problem constants
#define NB 128
#define NC 256
#define HX 31
#define WX 31
#define HC 25          // corr spatial (31-7+1)
#define WC 25
#define HO 23          // head output spatial (25-3+1)
#define WO 23
#define CHUNKS 16      // channel chunks per batch item -> 2048 blocks
#define CPB (NC / CHUNKS)    // 16 channels per block
#define GRP 8                // channels per group iteration (25 threads each) -> 2 even groups
#define ZCH 56               // z: 7 rows * 8 stride (16B-aligned rows)
#define WCH 48               // weights: 9 taps * 5 slots = 45, padded to 48
#define CCH (HC * WC)        // 625

#define NPIX (HO * WO)               // 529
#define HEAT_SZ (NB * NPIX)          // 67712
#define REG_SZ  (NB * 4 * NPIX)      // 270848
#define OUT_TOTAL (HEAT_SZ + REG_SZ) // 338560
#define NSTRIP (HO * 12)             // 276 two-pixel strips per image
#define PART_STRIDE (5 * NPIX)       // 2645 floats per (n,chunk) partial
#define WS_NEED ((size_t)NB * CHUNKS * PART_STRIDE * sizeof(float))

// unaligned-capable float4 (rows start at arbitrary dword offsets)
typedef float f4v __attribute__((ext_vector_type(4), aligned(4)));

// Fallback path only: writes bias into d_out (harness poisons d_out before launch).
__global__ void init_out_kernel(float* __restrict__ out,
                                const float* __restrict__ heat_b,
                                const float* __restrict__ reg_b) {
    int i = blockIdx.x * 256 + threadIdx.x;
    if (i >= OUT_TOTAL) return;
    if (i < HEAT_SZ) {
        out[i] = heat_b[0];
    } else {
        int j = i - HEAT_SZ;
        int o = (j / NPIX) & 3;
        out[i] = reg_b[o];
    }
}

// Reduce 16 per-chunk partials + bias -> final outputs. Overwrites poison fully.
__global__ void reduce_kernel(const float* __restrict__ part,
                              const float* __restrict__ heat_b,
                              const float* __restrict__ reg_b,
                              float* __restrict__ out) {
    int i = blockIdx.x * 256 + threadIdx.x;
    if (i >= OUT_TOTAL) return;
    int n, o, p;
    float b;
    if (i < HEAT_SZ) {
        n = i / NPIX; p = i - n * NPIX; o = 0; b = heat_b[0];
    } else {
        int j = i - HEAT_SZ;
        n = j / (4 * NPIX);
        int rm = j - n * 4 * NPIX;
        int r = rm / NPIX;
        p = rm - r * NPIX;
        o = 1 + r;
        b = reg_b[r];
    }
    const float* src = part + (size_t)n * CHUNKS * PART_STRIDE + o * NPIX + p;
    float s = b;
    #pragma unroll
    for (int c = 0; c < CHUNKS; ++c) s += src[(size_t)c * PART_STRIDE];
    out[i] = s;
}

// Fused exact-corr + head kernel, v5:
//  - CPB=16/GRP=8: two even corr groups (no tail pass)
//  - LDS ~24.9KB -> 6 blocks/CU possible; occupancy from LDS, NOT a VGPR clamp
//  - launch_bounds(256,4): v4's (256,6) forced VGPR=40 -> 4.4GB scratch spill
//  - head phase: NO w[48] register tile; weights transposed in LDS
//    (ws[ch][tap][slot], 5 contiguous floats per tap) read at use via
//    broadcast f4v+scalar -> head live set ~40 VGPRs
//  - USE_WS: exclusive partial outputs, no atomics
template <bool USE_WS>
__launch_bounds__(256, 4)
__global__ void fused_head_kernel(const float* __restrict__ xf,
                                  const float* __restrict__ zf,
                                  const float* __restrict__ hw,
                                  const float* __restrict__ rw,
                                  float* __restrict__ out) {
    __shared__ __align__(16) float cs[GRP * CCH + 8];   // 20.0 KB (+pad for strip overread)
    __shared__ __align__(16) float zs[GRP * ZCH];       // 1.8 KB
    __shared__ __align__(16) float ws[CPB * WCH];       // 3.0 KB

    const int tid = threadIdx.x;
    const int n = blockIdx.x >> 4;
    const int chunk = blockIdx.x & 15;
    const int cbase = chunk * CPB;

    // corr mapping: 25 threads/channel, each owns an exact 5x5 corr tile
    const int cl = tid / 25;               // channel-in-group (>=GRP -> idle)
    const int tt = tid % 25;
    const int tr = tt / 5, tc = tt % 5;
    const int i0 = tr * 5, j0 = tc * 5;

    // head mapping: 2-pixel strips; strip s -> row s/12, cols 2*(s%12), 2*(s%12)+1
    const int sA = tid;                       // 0..255, always valid (< 276)
    const int syA = sA / 12, sxA = sA - syA * 12;
    const int cA = 2 * sxA;
    const int offA = syA * WC + cA;
    const int sB = tid + 256;                 // valid only for tid < 20
    const bool hasB = (sB < NSTRIP);
    const int syB = sB / 12, sxB = sB - syB * 12;
    const int cB = 2 * sxB;
    const int offB = hasB ? (syB * WC + cB) : 0;

    float aH_A0 = 0.f, aH_A1 = 0.f, aH_B0 = 0.f, aH_B1 = 0.f;
    float aR_A0[4] = {0.f, 0.f, 0.f, 0.f};
    float aR_A1[4] = {0.f, 0.f, 0.f, 0.f};
    float aR_B0[4] = {0.f, 0.f, 0.f, 0.f};
    float aR_B1[4] = {0.f, 0.f, 0.f, 0.f};

    const float* xn = xf + ((size_t)n * NC + cbase) * (HX * WX);
    const float* zn = zf + ((size_t)n * NC + cbase) * 49;

    // ---- stage all 16 channels' head weights once, TRANSPOSED: [tap][slot] ----
    // slot 0 = heat, slot 1+o = reg o; tap's 5 weights contiguous at tap*5.
    for (int idx = tid; idx < CPB * 45; idx += 256) {
        int ch = idx / 45, j = idx - ch * 45;
        int c = cbase + ch;
        float v; int tap, slot;
        if (j < 9) {
            v = hw[c * 9 + j]; tap = j; slot = 0;
        } else {
            int o = (j - 9) / 9;
            int jj = (j - 9) - o * 9;
            v = rw[((size_t)o * NC + c) * 9 + jj];
            tap = jj; slot = 1 + o;
        }
        ws[ch * WCH + tap * 5 + slot] = v;
    }

    for (int g0 = 0; g0 < CPB; g0 += GRP) {
        // ---- stage z, rows padded to stride 8 ----
        for (int idx = tid; idx < GRP * 49; idx += 256) {
            int ch = idx / 49, q = idx - ch * 49;
            int u = q / 7, v = q - u * 7;
            zs[ch * ZCH + u * 8 + v] = zn[(size_t)(g0 + ch) * 49 + q];
        }
        __syncthreads();

        // ---- exact corr: x rows from global, pipelined one row ahead ----
        if (cl < GRP) {
            const float* xb = xn + (size_t)(g0 + cl) * (HX * WX) + i0 * WX + j0;
            const float* zb = zs + cl * ZCH;

            float cacc[5][5];
            #pragma unroll
            for (int r = 0; r < 5; ++r)
                #pragma unroll
                for (int b = 0; b < 5; ++b) cacc[r][b] = 0.f;

            f4v c0 = *(const f4v*)(xb);
            f4v c1 = *(const f4v*)(xb + 4);
            f4v c2 = *(const f4v*)(xb + 7);   // cols j0+7..j0+10 (max col 30)

            #pragma unroll
            for (int rl = 0; rl < 11; ++rl) {
                f4v n0, n1, n2;
                if (rl < 10) {
                    const float* rp = xb + (rl + 1) * WX;
                    n0 = *(const f4v*)(rp);
                    n1 = *(const f4v*)(rp + 4);
                    n2 = *(const f4v*)(rp + 7);
                }
                const float xr[11] = {c0.x, c0.y, c0.z, c0.w,
                                      c1.x, c1.y, c1.z, c1.w,
                                      c2.y, c2.z, c2.w};
                #pragma unroll
                for (int u = 0; u < 7; ++u) {
                    const int r = rl - u;           // folds at compile time
                    if (r >= 0 && r < 5) {
                        f4v za = *(const f4v*)(zb + u * 8);      // broadcast
                        f4v zc = *(const f4v*)(zb + u * 8 + 4);
                        const float zz[7] = {za.x, za.y, za.z, za.w,
                                             zc.x, zc.y, zc.z};
                        #pragma unroll
                        for (int v = 0; v < 7; ++v)
                            #pragma unroll
                            for (int b = 0; b < 5; ++b)
                                cacc[r][b] = fmaf(zz[v], xr[b + v], cacc[r][b]);
                    }
                }
                if (rl < 10) { c0 = n0; c1 = n1; c2 = n2; }
            }
            float* cb = cs + cl * CCH + i0 * WC + j0;
            #pragma unroll
            for (int r = 0; r < 5; ++r)
                #pragma unroll
                for (int b = 0; b < 5; ++b) cb[r * WC + b] = cacc[r][b];
        }
        __syncthreads();

        // ---- conv heads: 2-pixel strips, weights read per-tap from LDS (broadcast) ----
        for (int clc = 0; clc < GRP; ++clc) {
            const float* cc = cs + clc * CCH;
            const float* wt = ws + (g0 + clc) * WCH;

            {   // strip A (all threads)
                const float* base = cc + offA;
                #pragma unroll
                for (int dy = 0; dy < 3; ++dy) {
                    f4v f = *(const f4v*)(base + dy * WC);
                    #pragma unroll
                    for (int dx = 0; dx < 3; ++dx) {
                        const int k = dy * 3 + dx;
                        f4v wa = *(const f4v*)(wt + k * 5);  // heat,r0,r1,r2 (broadcast)
                        const float w4 = wt[k * 5 + 4];      // r3 (broadcast)
                        const float v0 = f[dx];
                        const float v1 = f[dx + 1];
                        aH_A0    = fmaf(v0, wa.x, aH_A0);
                        aH_A1    = fmaf(v1, wa.x, aH_A1);
                        aR_A0[0] = fmaf(v0, wa.y, aR_A0[0]);
                        aR_A1[0] = fmaf(v1, wa.y, aR_A1[0]);
                        aR_A0[1] = fmaf(v0, wa.z, aR_A0[1]);
                        aR_A1[1] = fmaf(v1, wa.z, aR_A1[1]);
                        aR_A0[2] = fmaf(v0, wa.w, aR_A0[2]);
                        aR_A1[2] = fmaf(v1, wa.w, aR_A1[2]);
                        aR_A0[3] = fmaf(v0, w4,   aR_A0[3]);
                        aR_A1[3] = fmaf(v1, w4,   aR_A1[3]);
                    }
                }
            }
            if (hasB) {   // strip B (tid < 20: only wave 0 pays)
                const float* base = cc + offB;
                #pragma unroll
                for (int dy = 0; dy < 3; ++dy) {
                    f4v f = *(const f4v*)(base + dy * WC);
                    #pragma unroll
                    for (int dx = 0; dx < 3; ++dx) {
                        const int k = dy * 3 + dx;
                        f4v wa = *(const f4v*)(wt + k * 5);
                        const float w4 = wt[k * 5 + 4];
                        const float v0 = f[dx];
                        const float v1 = f[dx + 1];
                        aH_B0    = fmaf(v0, wa.x, aH_B0);
                        aH_B1    = fmaf(v1, wa.x, aH_B1);
                        aR_B0[0] = fmaf(v0, wa.y, aR_B0[0]);
                        aR_B1[0] = fmaf(v1, wa.y, aR_B1[0]);
                        aR_B0[1] = fmaf(v0, wa.z, aR_B0[1]);
                        aR_B1[1] = fmaf(v1, wa.z, aR_B1[1]);
                        aR_B0[2] = fmaf(v0, wa.w, aR_B0[2]);
                        aR_B1[2] = fmaf(v1, wa.w, aR_B1[2]);
                        aR_B0[3] = fmaf(v0, w4,   aR_B0[3]);
                        aR_B1[3] = fmaf(v1, w4,   aR_B1[3]);
                    }
                }
            }
        }
        __syncthreads();
    }

    // ---- epilogue ----
    if (USE_WS) {
        // exclusive partial region for this (n, chunk): plain coalesced stores
        float* part = out + (size_t)(n * CHUNKS + chunk) * PART_STRIDE;
        const int pA = syA * WO + cA;
        part[pA] = aH_A0;
        #pragma unroll
        for (int o = 0; o < 4; ++o) part[(1 + o) * NPIX + pA] = aR_A0[o];
        if (cA + 1 < WO) {
            part[pA + 1] = aH_A1;
            #pragma unroll
            for (int o = 0; o < 4; ++o) part[(1 + o) * NPIX + pA + 1] = aR_A1[o];
        }
        if (hasB) {
            const int pB = syB * WO + cB;
            part[pB] = aH_B0;
            #pragma unroll
            for (int o = 0; o < 4; ++o) part[(1 + o) * NPIX + pB] = aR_B0[o];
            if (cB + 1 < WO) {
                part[pB + 1] = aH_B1;
                #pragma unroll
                for (int o = 0; o < 4; ++o) part[(1 + o) * NPIX + pB + 1] = aR_B1[o];
            }
        }
    } else {
        // atomic fallback (bias pre-written by init kernel)
        float* outH = out + n * NPIX;
        float* outR = out + HEAT_SZ + (size_t)n * 4 * NPIX;
        const int pA = syA * WO + cA;
        atomicAdd(&outH[pA], aH_A0);
        #pragma unroll
        for (int o = 0; o < 4; ++o) atomicAdd(&outR[o * NPIX + pA], aR_A0[o]);
        if (cA + 1 < WO) {
            atomicAdd(&outH[pA + 1], aH_A1);
            #pragma unroll
            for (int o = 0; o < 4; ++o) atomicAdd(&outR[o * NPIX + pA + 1], aR_A1[o]);
        }
        if (hasB) {
            const int pB = syB * WO + cB;
            atomicAdd(&outH[pB], aH_B0);
            #pragma unroll
            for (int o = 0; o < 4; ++o) atomicAdd(&outR[o * NPIX + pB], aR_B0[o]);
            if (cB + 1 < WO) {
                atomicAdd(&outH[pB + 1], aH_B1);
                #pragma unroll
                for (int o = 0; o < 4; ++o) atomicAdd(&outR[o * NPIX + pB + 1], aR_B1[o]);
            }
        }
    }
}

extern "C" void kernel_launch(void* const* d_in, const int* in_sizes, int n_in,
                              void* d_out, int out_size, void* d_ws, size_t ws_size,
                              hipStream_t stream) {
    const float* x_f    = (const float*)d_in[0];
    const float* z_f    = (const float*)d_in[1];
    const float* heat_w = (const float*)d_in[2];
    const float* heat_b = (const float*)d_in[3];
    const float* reg_w  = (const float*)d_in[4];
    const float* reg_b  = (const float*)d_in[5];
    float* out = (float*)d_out;

    if (d_ws != nullptr && ws_size >= WS_NEED) {
        fused_head_kernel<true><<<NB * CHUNKS, 256, 0, stream>>>(
            x_f, z_f, heat_w, reg_w, (float*)d_ws);
        reduce_kernel<<<(OUT_TOTAL + 255) / 256, 256, 0, stream>>>(
            (const float*)d_ws, heat_b, reg_b, out);
    } else {
        init_out_kernel<<<(OUT_TOTAL + 255) / 256, 256, 0, stream>>>(out, heat_b, reg_b);
        fused_head_kernel<false><<<NB * CHUNKS, 256, 0, stream>>>(
            x_f, z_f, heat_w, reg_w, out);
    }
}

// Round 5
// 258.327 us; speedup vs baseline: 5.8120x; 4.6606x over previous
//
#include <hip/hip_runtime.h>

// Problem constants
#define NB 128
#define NC 256
#define HX 31
#define WX 31
#define HC 25          // corr spatial (31-7+1)
#define WC 25
#define HO 23          // head output spatial (25-3+1)
#define WO 23
#define CHUNKS 16      // channel chunks per batch item -> 2048 blocks
#define CPB (NC / CHUNKS)    // 16 channels per block
#define GRP 8                // channels per group iteration -> 2 even groups
#define ZCH 56               // z: 7 rows * 8 stride (16B-aligned rows)
#define WCH 48               // weights: 45 padded to 48 (12 float4), v3 layout
#define CCH (HC * WC)        // 625

#define NPIX (HO * WO)               // 529
#define HEAT_SZ (NB * NPIX)          // 67712
#define REG_SZ  (NB * 4 * NPIX)      // 270848
#define OUT_TOTAL (HEAT_SZ + REG_SZ) // 338560
#define NSTRIP3 (HO * 8)             // 184 three-pixel strips (last in row = 2)
#define PART_STRIDE (5 * NPIX)       // 2645 floats per (n,chunk) partial
#define WS_NEED ((size_t)NB * CHUNKS * PART_STRIDE * sizeof(float))

// unaligned-capable float4 (rows start at arbitrary dword offsets)
typedef float f4v __attribute__((ext_vector_type(4), aligned(4)));

// Fallback path only: writes bias into d_out (harness poisons d_out before launch).
__global__ void init_out_kernel(float* __restrict__ out,
                                const float* __restrict__ heat_b,
                                const float* __restrict__ reg_b) {
    int i = blockIdx.x * 256 + threadIdx.x;
    if (i >= OUT_TOTAL) return;
    if (i < HEAT_SZ) {
        out[i] = heat_b[0];
    } else {
        int j = i - HEAT_SZ;
        int o = (j / NPIX) & 3;
        out[i] = reg_b[o];
    }
}

// Reduce 16 per-chunk partials + bias -> final outputs. Overwrites poison fully.
__global__ void reduce_kernel(const float* __restrict__ part,
                              const float* __restrict__ heat_b,
                              const float* __restrict__ reg_b,
                              float* __restrict__ out) {
    int i = blockIdx.x * 256 + threadIdx.x;
    if (i >= OUT_TOTAL) return;
    int n, o, p;
    float b;
    if (i < HEAT_SZ) {
        n = i / NPIX; p = i - n * NPIX; o = 0; b = heat_b[0];
    } else {
        int j = i - HEAT_SZ;
        n = j / (4 * NPIX);
        int rm = j - n * 4 * NPIX;
        int r = rm / NPIX;
        p = rm - r * NPIX;
        o = 1 + r;
        b = reg_b[r];
    }
    const float* src = part + (size_t)n * CHUNKS * PART_STRIDE + o * NPIX + p;
    float s = b;
    #pragma unroll
    for (int c = 0; c < CHUNKS; ++c) s += src[(size_t)c * PART_STRIDE];
    out[i] = s;
}

// Fused exact-corr + head kernel, v6:
//  - corr phase + w[48] tile: byte-identical to v3 (proven 64 VGPR, no scratch)
//  - head phase: 3-pixel strips, ONE accumulator set (15 floats = v3's count);
//    per channel: 3 rows x (f4v + scalar) = 6 LDS reads for 3 pixels (vs 27/pixel)
//  - CHUNKS=16/GRP=8: LDS 24.9KB -> 6 blocks/CU, 2048 blocks
//  - USE_WS: exclusive partial outputs, no atomics
template <bool USE_WS>
__launch_bounds__(256, 4)
__global__ void fused_head_kernel(const float* __restrict__ xf,
                                  const float* __restrict__ zf,
                                  const float* __restrict__ hw,
                                  const float* __restrict__ rw,
                                  float* __restrict__ out) {
    __shared__ __align__(16) float cs[GRP * CCH + 8];   // 20.0 KB (+pad: tail-strip overread)
    __shared__ __align__(16) float zs[GRP * ZCH];       // 1.8 KB
    __shared__ __align__(16) float ws[CPB * WCH];       // 3.0 KB

    const int tid = threadIdx.x;
    const int n = blockIdx.x >> 4;
    const int chunk = blockIdx.x & 15;
    const int cbase = chunk * CPB;

    // corr mapping: 25 threads/channel, each owns an exact 5x5 corr tile
    const int cl = tid / 25;               // channel-in-group (>=GRP -> idle)
    const int tt = tid % 25;
    const int tr = tt / 5, tc = tt % 5;
    const int i0 = tr * 5, j0 = tc * 5;

    // head mapping: 3-pixel strips. strip sid -> row sid/8, cols 3*(sid%8)..+2
    // (last strip in a row covers only 2 valid pixels; 3rd is computed, not stored)
    const bool hasS = (tid < NSTRIP3);     // threads 184..255 idle in head phase
    const int sy = tid >> 3;               // 0..22
    const int sx = tid & 7;                // 0..7
    const int cx = sx * 3;                 // 0,3,...,21
    const int offS = sy * WC + cx;

    float accH[3] = {0.f, 0.f, 0.f};
    float accR[4][3] = {{0.f,0.f,0.f},{0.f,0.f,0.f},{0.f,0.f,0.f},{0.f,0.f,0.f}};

    const float* xn = xf + ((size_t)n * NC + cbase) * (HX * WX);
    const float* zn = zf + ((size_t)n * NC + cbase) * 49;

    // ---- stage all 16 channels' head weights once (v3 layout) ----
    for (int idx = tid; idx < CPB * 45; idx += 256) {
        int ch = idx / 45, j = idx - ch * 45;
        int c = cbase + ch;
        float v;
        if (j < 9) {
            v = hw[c * 9 + j];
        } else {
            int o = (j - 9) / 9;
            int jj = (j - 9) - o * 9;
            v = rw[((size_t)o * NC + c) * 9 + jj];
        }
        ws[ch * WCH + j] = v;
    }

    for (int g0 = 0; g0 < CPB; g0 += GRP) {
        // ---- stage z, rows padded to stride 8 for aligned reads ----
        for (int idx = tid; idx < GRP * 49; idx += 256) {
            int ch = idx / 49, q = idx - ch * 49;
            int u = q / 7, v = q - u * 7;
            zs[ch * ZCH + u * 8 + v] = zn[(size_t)(g0 + ch) * 49 + q];
        }
        __syncthreads();

        // ---- exact corr: x rows from global, pipelined one row ahead (v3-identical) ----
        if (cl < GRP) {
            const float* xb = xn + (size_t)(g0 + cl) * (HX * WX) + i0 * WX + j0;
            const float* zb = zs + cl * ZCH;

            float cacc[5][5];
            #pragma unroll
            for (int r = 0; r < 5; ++r)
                #pragma unroll
                for (int b = 0; b < 5; ++b) cacc[r][b] = 0.f;

            f4v c0 = *(const f4v*)(xb);
            f4v c1 = *(const f4v*)(xb + 4);
            f4v c2 = *(const f4v*)(xb + 7);   // cols j0+7..j0+10 (max col 30)

            #pragma unroll
            for (int rl = 0; rl < 11; ++rl) {
                f4v n0, n1, n2;
                if (rl < 10) {
                    const float* rp = xb + (rl + 1) * WX;
                    n0 = *(const f4v*)(rp);
                    n1 = *(const f4v*)(rp + 4);
                    n2 = *(const f4v*)(rp + 7);
                }
                const float xr[11] = {c0.x, c0.y, c0.z, c0.w,
                                      c1.x, c1.y, c1.z, c1.w,
                                      c2.y, c2.z, c2.w};
                #pragma unroll
                for (int u = 0; u < 7; ++u) {
                    const int r = rl - u;           // folds at compile time
                    if (r >= 0 && r < 5) {
                        f4v za = *(const f4v*)(zb + u * 8);      // broadcast
                        f4v zc = *(const f4v*)(zb + u * 8 + 4);
                        const float zz[7] = {za.x, za.y, za.z, za.w,
                                             zc.x, zc.y, zc.z};
                        #pragma unroll
                        for (int v = 0; v < 7; ++v)
                            #pragma unroll
                            for (int b = 0; b < 5; ++b)
                                cacc[r][b] = fmaf(zz[v], xr[b + v], cacc[r][b]);
                    }
                }
                if (rl < 10) { c0 = n0; c1 = n1; c2 = n2; }
            }
            float* cb = cs + cl * CCH + i0 * WC + j0;
            #pragma unroll
            for (int r = 0; r < 5; ++r)
                #pragma unroll
                for (int b = 0; b < 5; ++b) cb[r * WC + b] = cacc[r][b];
        }
        __syncthreads();

        // ---- conv heads: 3-pixel strips, w[48] broadcast tile (v3 pattern) ----
        if (hasS) {
            for (int clc = 0; clc < GRP; ++clc) {
                float w[48];
                {
                    const f4v* wp = (const f4v*)(ws + (size_t)(g0 + clc) * WCH);
                    #pragma unroll
                    for (int q = 0; q < 12; ++q) {     // broadcast b128
                        f4v t = wp[q];
                        w[q * 4 + 0] = t.x; w[q * 4 + 1] = t.y;
                        w[q * 4 + 2] = t.z; w[q * 4 + 3] = t.w;
                    }
                }
                const float* base = cs + clc * CCH + offS;

                #pragma unroll
                for (int dy = 0; dy < 3; ++dy) {
                    f4v f = *(const f4v*)(base + dy * WC);   // cols cx..cx+3
                    const float f4 = base[dy * WC + 4];      // col cx+4
                    #pragma unroll
                    for (int dx = 0; dx < 3; ++dx) {
                        const int k = dy * 3 + dx;
                        #pragma unroll
                        for (int px = 0; px < 3; ++px) {
                            const int e = dx + px;           // 0..4, static
                            const float cv = (e < 4) ? f[e] : f4;
                            accH[px]    = fmaf(cv, w[k],      accH[px]);
                            accR[0][px] = fmaf(cv, w[9 + k],  accR[0][px]);
                            accR[1][px] = fmaf(cv, w[18 + k], accR[1][px]);
                            accR[2][px] = fmaf(cv, w[27 + k], accR[2][px]);
                            accR[3][px] = fmaf(cv, w[36 + k], accR[3][px]);
                        }
                    }
                }
            }
        }
        __syncthreads();
    }

    // ---- epilogue ----
    if (!hasS) return;
    const int p = sy * WO + cx;
    const bool full = (sx < 7);          // last strip in row has only 2 pixels

    if (USE_WS) {
        // exclusive partial region for this (n, chunk): plain stores
        float* part = out + (size_t)(n * CHUNKS + chunk) * PART_STRIDE;
        part[p + 0] = accH[0];
        part[p + 1] = accH[1];
        if (full) part[p + 2] = accH[2];
        #pragma unroll
        for (int o = 0; o < 4; ++o) {
            float* pr = part + (1 + o) * NPIX + p;
            pr[0] = accR[o][0];
            pr[1] = accR[o][1];
            if (full) pr[2] = accR[o][2];
        }
    } else {
        // atomic fallback (bias pre-written by init kernel)
        float* outH = out + n * NPIX + p;
        float* outR = out + HEAT_SZ + (size_t)n * 4 * NPIX + p;
        atomicAdd(&outH[0], accH[0]);
        atomicAdd(&outH[1], accH[1]);
        if (full) atomicAdd(&outH[2], accH[2]);
        #pragma unroll
        for (int o = 0; o < 4; ++o) {
            float* pr = outR + o * NPIX;
            atomicAdd(&pr[0], accR[o][0]);
            atomicAdd(&pr[1], accR[o][1]);
            if (full) atomicAdd(&pr[2], accR[o][2]);
        }
    }
}

extern "C" void kernel_launch(void* const* d_in, const int* in_sizes, int n_in,
                              void* d_out, int out_size, void* d_ws, size_t ws_size,
                              hipStream_t stream) {
    const float* x_f    = (const float*)d_in[0];
    const float* z_f    = (const float*)d_in[1];
    const float* heat_w = (const float*)d_in[2];
    const float* heat_b = (const float*)d_in[3];
    const float* reg_w  = (const float*)d_in[4];
    const float* reg_b  = (const float*)d_in[5];
    float* out = (float*)d_out;

    if (d_ws != nullptr && ws_size >= WS_NEED) {
        fused_head_kernel<true><<<NB * CHUNKS, 256, 0, stream>>>(
            x_f, z_f, heat_w, reg_w, (float*)d_ws);
        reduce_kernel<<<(OUT_TOTAL + 255) / 256, 256, 0, stream>>>(
            (const float*)d_ws, heat_b, reg_b, out);
    } else {
        init_out_kernel<<<(OUT_TOTAL + 255) / 256, 256, 0, stream>>>(out, heat_b, reg_b);
        fused_head_kernel<false><<<NB * CHUNKS, 256, 0, stream>>>(
            x_f, z_f, heat_w, reg_w, out);
    }
}